// Round 1
// baseline (546.369 us; speedup 1.0000x reference)
//
#include <hip/hip_runtime.h>
#include <stdint.h>

// ---------------------------------------------------------------------------
// d128snn_delays: 3x DCLS conv (L=25 causal taps, Gaussian-interpolated) with
// BN+ReLU between layers and softmax-sum epilogue.
//   x: (B=128, T=100, C=700) f32 -> out: (128, 20) f32
// Strategy: materialize dense kernels as bf16 in [d][o][i] layout, run each
// conv as 25 row-shifted bf16 MFMA GEMMs (fp32 accum), m97-style 128x128
// tiles with global_load_lds(16B) staging + XOR LDS swizzle, K-split over
// delays with fp32 atomicAdd epilogue.
// ---------------------------------------------------------------------------

#define T_LEN 100
#define B_SZ  128
#define TPAD  (T_LEN + 24)   // 24 zero rows of left (causal) padding

typedef __bf16 v8bf __attribute__((ext_vector_type(8)));
typedef float  v4f  __attribute__((ext_vector_type(4)));

// async global->LDS, 16B per lane; LDS dest = wave-uniform base + lane*16
__device__ __forceinline__ void gl_lds16(const void* g, void* l) {
  __builtin_amdgcn_global_load_lds(
      (const __attribute__((address_space(1))) char*)g,
      (__attribute__((address_space(3))) char*)l, 16, 0, 0);
}

// ---------------------------------------------------------------------------
// Build dense DCLS kernel, bf16, layout Kd[d][o][i] (i fastest; pre-transposed
// so the GEMM B-tile stages contiguously in k=i). d = 24 - l (y[t] += Kd[d]*x[t-d]).
// Pads (o >= COUT or i >= CIN) written as zero.
// ---------------------------------------------------------------------------
__global__ void build_kd(const float* __restrict__ W, const float* __restrict__ P,
                         __bf16* __restrict__ Kd, int CIN, int CINP, int COUT, int COUTP) {
  int o = blockIdx.x;  // < COUTP
  for (int i = threadIdx.x; i < CINP; i += blockDim.x) {
    bool valid = (o < COUT) && (i < CIN);
    float w = valid ? W[(size_t)o * CIN + i] : 0.f;
    float p = valid ? P[(size_t)o * CIN + i] : 0.f;
    float k[25];
    float s = 0.f;
#pragma unroll
    for (int l = 0; l < 25; ++l) {
      float g = ((float)(l - 12) - p) * (1.f / 12.f);
      float e = expf(-0.5f * g * g);
      k[l] = e; s += e;
    }
    float scale = w / (s + 1e-7f);
#pragma unroll
    for (int l = 0; l < 25; ++l) {
      Kd[(size_t)(24 - l) * COUTP * CINP + (size_t)o * CINP + i] = (__bf16)(k[l] * scale);
    }
  }
}

// x (B,T,C=700) f32 -> Xpad (TPAD,128,704) bf16 at row t+24 (pads stay zero)
__global__ void fill_x(const float* __restrict__ x, __bf16* __restrict__ Xp) {
  int tb = blockIdx.x;           // 12800
  int t = tb >> 7, b = tb & 127;
  const float* src = x + ((size_t)b * T_LEN + t) * 700;
  __bf16* dst = Xp + ((size_t)(t + 24) * B_SZ + b) * 704;
  for (int c = threadIdx.x; c < 700; c += 256) dst[c] = (__bf16)src[c];
}

// ---------------------------------------------------------------------------
// GEMM: Y[(t*128+b), o] += sum_{d in [d0,d1)} sum_i X[(t+24-d)*128+b, i] * Kd[d][o][i]
// BLK_M=128 (one t, all b), BLK_N cols, BK=32. 4 waves.
// LDS layout [row][kgroup^(row&3)] (16B groups) -> uniform 4-way ds_read_b128.
// ---------------------------------------------------------------------------
template <int CINP, int BLK_N, int WROWS, int WCOLS>
__global__ __launch_bounds__(256, 3)
void gemm_dcls(const __bf16* __restrict__ X,   // (TPAD, 128, CINP)
               const __bf16* __restrict__ Kd,  // (25, COUTP, CINP)
               float* __restrict__ Y,          // (12800, COUTP), zero-init, atomic accum
               int COUTP) {
  constexpr int WM = 128 / WROWS;
  constexpr int WN = BLK_N / WCOLS;
  constexpr int RM = WM / 16;
  constexpr int RN = WN / 16;
  __shared__ __align__(16) __bf16 sA[128 * 32];
  __shared__ __align__(16) __bf16 sB[BLK_N * 32];

  const int tid = threadIdx.x;
  const int w = tid >> 6, lane = tid & 63;
  const int q = lane >> 4, ln = lane & 15;
  const int wrow = w / WCOLS, wcol = w % WCOLS;
  const int srow = lane >> 2;   // row within a 16-row staging issue
  const int skg = lane & 3;     // physical kgroup slot

  const int t0 = blockIdx.x;
  const int oc = blockIdx.y * BLK_N;
  const int KZ = gridDim.z;
  const int d0 = (25 * (int)blockIdx.z) / KZ;
  const int d1 = (25 * ((int)blockIdx.z + 1)) / KZ;

  v4f acc[RM][RN];
#pragma unroll
  for (int a = 0; a < RM; ++a)
#pragma unroll
    for (int b = 0; b < RN; ++b) acc[a][b] = v4f{0.f, 0.f, 0.f, 0.f};

  for (int d = d0; d < d1; ++d) {
    const __bf16* Abase = X + (size_t)(t0 + 24 - d) * B_SZ * CINP;
    const __bf16* Bbase = Kd + ((size_t)d * COUTP + oc) * CINP;
    for (int ic = 0; ic < CINP; ic += 32) {
      // stage A: 8 issues x (16 rows x 32ch = 1KB); wave w takes issues w, w+4
      for (int j = w; j < 8; j += 4) {
        int m = j * 16 + srow;
        int kg = skg ^ (m & 3);  // fetch logical kgroup that lands in slot skg
        gl_lds16(Abase + (size_t)m * CINP + ic + kg * 8, &sA[j * 512]);
      }
      // stage B: BLK_N/16 issues
      for (int j = w; j < BLK_N / 16; j += 4) {
        int n = j * 16 + srow;
        int kg = skg ^ (n & 3);
        gl_lds16(Bbase + (size_t)n * CINP + ic + kg * 8, &sB[j * 512]);
      }
      __syncthreads();  // compiler emits vmcnt(0) drain before s_barrier

      v8bf af[RM], bfr[RN];
#pragma unroll
      for (int a = 0; a < RM; ++a) {
        int m = wrow * WM + a * 16 + ln;
        af[a] = *(const v8bf*)&sA[m * 32 + ((q ^ (m & 3)) * 8)];
      }
#pragma unroll
      for (int b = 0; b < RN; ++b) {
        int n = wcol * WN + b * 16 + ln;
        bfr[b] = *(const v8bf*)&sB[n * 32 + ((q ^ (n & 3)) * 8)];
      }
#pragma unroll
      for (int a = 0; a < RM; ++a)
#pragma unroll
        for (int b = 0; b < RN; ++b)
          acc[a][b] = __builtin_amdgcn_mfma_f32_16x16x32_bf16(af[a], bfr[b], acc[a][b], 0, 0, 0);
      __syncthreads();
    }
  }

  // epilogue: C/D layout col=lane&15, row=quad*4+reg (m89-verified)
#pragma unroll
  for (int a = 0; a < RM; ++a) {
#pragma unroll
    for (int b = 0; b < RN; ++b) {
      int col = oc + wcol * WN + b * 16 + ln;
#pragma unroll
      for (int r = 0; r < 4; ++r) {
        int m = wrow * WM + a * 16 + q * 4 + r;
        atomicAdd(&Y[(size_t)(t0 * B_SZ + m) * COUTP + col], acc[a][b][r]);
      }
    }
  }
}

// BN stats: per-channel sum/sumsq over (T*B)=12800 rows, C=256. Coalesced.
__global__ void bn_stats(const float* __restrict__ h, float* __restrict__ stats) {
  int c = threadIdx.x;                       // 256
  size_t r0 = (size_t)blockIdx.x * 128;      // 100 blocks x 128 rows
  float s = 0.f, ss = 0.f;
  for (int r = 0; r < 128; ++r) {
    float v = h[(r0 + r) * 256 + c];
    s += v; ss += v * v;
  }
  atomicAdd(&stats[c], s);
  atomicAdd(&stats[256 + c], ss);
}

// normalize + relu + bf16, write into time-padded next-layer input
__global__ void bn_apply_relu(const float* __restrict__ h, const float* __restrict__ stats,
                              const float* __restrict__ gamma, const float* __restrict__ beta,
                              __bf16* __restrict__ hpad) {
  int c = threadIdx.x;
  size_t row = blockIdx.x;  // 0..12799
  float mean = stats[c] * (1.f / 12800.f);
  float var = stats[256 + c] * (1.f / 12800.f) - mean * mean;
  float inv = rsqrtf(var + 1e-5f) * gamma[c];
  float v = (h[row * 256 + c] - mean) * inv + beta[c];
  v = fmaxf(v, 0.f);
  hpad[(row + (size_t)24 * B_SZ) * 256 + c] = (__bf16)v;
}

// softmax over 20 logits (stride-32 rows), sum over T via atomics
__global__ void softmax_sum(const float* __restrict__ h3, float* __restrict__ out) {
  int b = threadIdx.x;  // 128
  int t = blockIdx.x;   // 100
  const float* r = h3 + ((size_t)t * B_SZ + b) * 32;
  float v[20], m = -1e30f;
#pragma unroll
  for (int o = 0; o < 20; ++o) { v[o] = r[o]; m = fmaxf(m, v[o]); }
  float s = 0.f;
#pragma unroll
  for (int o = 0; o < 20; ++o) { v[o] = expf(v[o] - m); s += v[o]; }
  float inv = 1.f / s;
#pragma unroll
  for (int o = 0; o < 20; ++o) atomicAdd(&out[b * 20 + o], v[o] * inv);
}

// ---------------------------------------------------------------------------

extern "C" void kernel_launch(void* const* d_in, const int* in_sizes, int n_in,
                              void* d_out, int out_size, void* d_ws, size_t ws_size,
                              hipStream_t stream) {
  const float* x  = (const float*)d_in[0];
  const float* W1 = (const float*)d_in[1];
  const float* P1 = (const float*)d_in[2];
  const float* W2 = (const float*)d_in[3];
  const float* P2 = (const float*)d_in[4];
  const float* W3 = (const float*)d_in[5];
  const float* P3 = (const float*)d_in[6];
  const float* g1 = (const float*)d_in[7];
  const float* b1 = (const float*)d_in[8];
  const float* g2 = (const float*)d_in[9];
  const float* b2 = (const float*)d_in[10];
  float* out = (float*)d_out;

  // workspace layout (all 256B-aligned sizes); zeroed region first
  constexpr size_t XPAD_B  = (size_t)TPAD * B_SZ * 704 * 2;   // 22,347,776
  constexpr size_t HPAD_B  = (size_t)TPAD * B_SZ * 256 * 2;   //  8,126,464
  constexpr size_t HF_B    = (size_t)12800 * 256 * 4;         // 13,107,200
  constexpr size_t H3F_B   = (size_t)12800 * 32 * 4;          //  1,638,400
  constexpr size_t STATS_B = 4096;                            // 2 layers x 512 f32
  constexpr size_t K1_B    = (size_t)25 * 256 * 704 * 2;      //  9,011,200
  constexpr size_t K2_B    = (size_t)25 * 256 * 256 * 2;      //  3,276,800
  constexpr size_t K3_B    = (size_t)25 * 32 * 256 * 2;       //    409,600
  constexpr size_t ZERO_B  = XPAD_B + 2 * HPAD_B + 2 * HF_B + H3F_B + STATS_B;
  constexpr size_t TOTAL_B = ZERO_B + K1_B + K2_B + K3_B;     // ~79.2 MB
  if (ws_size < TOTAL_B) return;  // deterministic guard

  char* ws = (char*)d_ws;
  __bf16* Xpad   = (__bf16*)(ws);
  __bf16* h1pad  = (__bf16*)(ws + XPAD_B);
  __bf16* h2pad  = (__bf16*)(ws + XPAD_B + HPAD_B);
  float*  h1f    = (float*)(ws + XPAD_B + 2 * HPAD_B);
  float*  h2f    = (float*)(ws + XPAD_B + 2 * HPAD_B + HF_B);
  float*  h3f    = (float*)(ws + XPAD_B + 2 * HPAD_B + 2 * HF_B);
  float*  stats1 = (float*)(ws + XPAD_B + 2 * HPAD_B + 2 * HF_B + H3F_B);
  float*  stats2 = stats1 + 512;
  __bf16* K1 = (__bf16*)(ws + ZERO_B);
  __bf16* K2 = (__bf16*)(ws + ZERO_B + K1_B);
  __bf16* K3 = (__bf16*)(ws + ZERO_B + K1_B + K2_B);

  // zero pads, atomic targets, stats, output (ws is poisoned 0xAA each call)
  hipMemsetAsync(ws, 0, ZERO_B, stream);
  hipMemsetAsync(out, 0, (size_t)out_size * 4, stream);

  // dense kernels (bf16, [d][o][i])
  build_kd<<<dim3(256), 256, 0, stream>>>(W1, P1, K1, 700, 704, 256, 256);
  build_kd<<<dim3(256), 256, 0, stream>>>(W2, P2, K2, 256, 256, 256, 256);
  build_kd<<<dim3(32),  256, 0, stream>>>(W3, P3, K3, 256, 256, 20, 32);

  // x -> padded bf16 (T,B,C) layout
  fill_x<<<dim3(12800), 256, 0, stream>>>(x, Xpad);

  // layer 1: (12800 x 704*25) @ -> (12800 x 256)
  gemm_dcls<704, 128, 2, 2><<<dim3(100, 2, 4), 256, 0, stream>>>(Xpad, K1, h1f, 256);
  bn_stats<<<dim3(100), 256, 0, stream>>>(h1f, stats1);
  bn_apply_relu<<<dim3(12800), 256, 0, stream>>>(h1f, stats1, g1, b1, h1pad);

  // layer 2
  gemm_dcls<256, 128, 2, 2><<<dim3(100, 2, 4), 256, 0, stream>>>(h1pad, K2, h2f, 256);
  bn_stats<<<dim3(100), 256, 0, stream>>>(h2f, stats2);
  bn_apply_relu<<<dim3(12800), 256, 0, stream>>>(h2f, stats2, g2, b2, h2pad);

  // layer 3 (Cout padded 20->32)
  gemm_dcls<256, 32, 4, 1><<<dim3(100, 1, 4), 256, 0, stream>>>(h2pad, K3, h3f, 32);

  // softmax over channels, sum over time
  softmax_sum<<<dim3(100), 128, 0, stream>>>(h3f, out);
}